// Round 8
// baseline (336.009 us; speedup 1.0000x reference)
//
#include <hip/hip_runtime.h>
#include <math.h>

#define B_ 8
#define T_ 1000
#define C_ 8
#define F_ 257
#define A_ 320
#define TH_ 500   // half of T; 500 = 125*4 exactly, keeps float4 alignment

// ---------------- Kernel 1: (B,T,C,F) -> (B,F,C,T) interleaved float2 ----------
__global__ __launch_bounds__(256) void k_transpose(
    const float* __restrict__ dre, const float* __restrict__ dim_,
    float2* __restrict__ xt) {
  __shared__ float2 tile[32][33];
  int bc = blockIdx.z;
  int b = bc >> 3, c = bc & 7;
  int t0 = blockIdx.y * 32, f0 = blockIdx.x * 32;
  int tx = threadIdx.x, ty = threadIdx.y;
#pragma unroll
  for (int j = 0; j < 4; ++j) {
    int t = t0 + ty + j * 8, f = f0 + tx;
    if (t < T_ && f < F_) {
      size_t idx = ((size_t)(b * T_ + t) * C_ + c) * F_ + f;
      tile[ty + j * 8][tx] = make_float2(dre[idx], dim_[idx]);
    }
  }
  __syncthreads();
#pragma unroll
  for (int j = 0; j < 4; ++j) {
    int f = f0 + ty + j * 8, t = t0 + tx;
    if (t < T_ && f < F_) {
      xt[((size_t)(b * F_ + f) * C_ + c) * T_ + t] = tile[tx][ty + j * 8];
    }
  }
}

// ---------------- Kernel 2: partial PSDs — lane owns one (c,e) pair ------------
// No LDS, no barriers, no shfl, no reduction. Wave = (bf, half); lane l=(c,e)
// accumulates psd_s/n[c][e] over its 500 t's with pure FMAs. Loads broadcast
// through L1 (8 distinct 16B addrs per instr). 4112 waves = 4/SIMD resident.
#define PSD_T(XCX, XCY, XEX, XEY, M, N) do {                \
    float ysx = (M) * (XCX), ysy = (M) * (XCY);             \
    as.x += ysx * (XEX) + ysy * (XEY);                      \
    as.y += ysy * (XEX) - ysx * (XEY);                      \
    float ynx = (N) * (XCX), yny = (N) * (XCY);             \
    an.x += ynx * (XEX) + yny * (XEY);                      \
    an.y += yny * (XEX) - ynx * (XEY);                      \
  } while (0)

__global__ __launch_bounds__(256) void k_psd(
    const float2* __restrict__ xt,
    const float* __restrict__ ms, const float* __restrict__ mn,
    float2* __restrict__ psp, float2* __restrict__ pnp,
    float* __restrict__ msum, float* __restrict__ nsum) {
  int wid = blockIdx.x * 4 + (threadIdx.x >> 6);   // 0..4111
  int bf = wid >> 1, half = wid & 1;
  int l = threadIdx.x & 63;
  int c = l >> 3, e = l & 7;

  const float2* xbase = xt + (size_t)bf * (C_ * T_);
  const float4* xc4 = (const float4*)(xbase + c * T_ + half * TH_);  // 2 float2/float4
  const float4* xe4 = (const float4*)(xbase + e * T_ + half * TH_);
  const float4* ms4 = (const float4*)(ms + (size_t)bf * (C_ * T_) + c * T_ + half * TH_);
  const float4* mn4 = (const float4*)(mn + (size_t)bf * (C_ * T_) + c * T_ + half * TH_);

  float2 as = make_float2(0.f, 0.f), an = make_float2(0.f, 0.f);
  float ss = 0.f, sn = 0.f;

  // prologue: iter 0
  float4 xcA0 = xc4[0], xcA1 = xc4[1];
  float4 xeA0 = xe4[0], xeA1 = xe4[1];
  float4 msA = ms4[0], mnA = mn4[0];

  for (int i = 0; i < 125; ++i) {
    int j = (i < 124) ? (i + 1) : 124;     // clamped prefetch (stays in-bounds)
    float4 xcB0 = xc4[2 * j], xcB1 = xc4[2 * j + 1];
    float4 xeB0 = xe4[2 * j], xeB1 = xe4[2 * j + 1];
    float4 msB = ms4[j], mnB = mn4[j];

    PSD_T(xcA0.x, xcA0.y, xeA0.x, xeA0.y, msA.x, mnA.x);
    PSD_T(xcA0.z, xcA0.w, xeA0.z, xeA0.w, msA.y, mnA.y);
    PSD_T(xcA1.x, xcA1.y, xeA1.x, xeA1.y, msA.z, mnA.z);
    PSD_T(xcA1.z, xcA1.w, xeA1.z, xeA1.w, msA.w, mnA.w);
    ss += (msA.x + msA.y) + (msA.z + msA.w);
    sn += (mnA.x + mnA.y) + (mnA.z + mnA.w);

    xcA0 = xcB0; xcA1 = xcB1; xeA0 = xeB0; xeA1 = xeB1;
    msA = msB; mnA = mnB;
  }

  size_t obase = ((size_t)bf * 2 + half) * 64;
  psp[obase + l] = as;
  pnp[obase + l] = an;
  if (e == 0) {
    msum[((size_t)bf * 2 + half) * 8 + c] = ss;
    nsum[((size_t)bf * 2 + half) * 8 + c] = sn;
  }
}

// ---------------- Kernel 2b: combine halves -> attention features --------------
__global__ __launch_bounds__(64) void k_comb(
    const float2* __restrict__ psp, const float* __restrict__ msum,
    float* __restrict__ feat) {
  int bf = blockIdx.x;
  int b = bf / F_;
  int f = bf - b * F_;
  int l = threadIdx.x;
  int c = l >> 3, e = l & 7;

  float2 s0 = psp[(size_t)bf * 128 + l];
  float2 s1 = psp[(size_t)bf * 128 + 64 + l];
  float ssum = msum[bf * 16 + c] + msum[bf * 16 + 8 + c];
  float inv = 1.f / (ssum + 1e-6f);
  float fr = (e == c) ? 0.f : (s0.x + s1.x) * inv;
  float fi = (e == c) ? 0.f : (s0.y + s1.y) * inv;
#pragma unroll
  for (int s = 4; s >= 1; s >>= 1) { fr += __shfl_xor(fr, s); fi += __shfl_xor(fi, s); }
  if (e == 0) {
    fr *= (1.f / 7.f); fi *= (1.f / 7.f);
    feat[(b * C_ + c) * F_ + f] = sqrtf(fr * fr + fi * fi);
  }
}

// ---------------- Kernel 3: attention MLP partial logits ----------------------
__global__ __launch_bounds__(64) void k_attn(
    const float* __restrict__ feat, const float* __restrict__ wmlp,
    const float* __restrict__ bmlp, const float* __restrict__ wgv,
    float* __restrict__ e_part) {
  __shared__ float fl[C_ * F_];   // 8224 B
  int b = blockIdx.x, p = blockIdx.y;
  int tid = threadIdx.x;
  for (int i = tid; i < C_ * F_; i += 64) fl[i] = feat[b * C_ * F_ + i];
  __syncthreads();

  int a = p * 64 + tid;           // A = 320 = 5*64 exactly
  const float* wr = wmlp + a * F_;
  float acc[C_];
  float bm = bmlp[a];
#pragma unroll
  for (int c = 0; c < C_; ++c) acc[c] = bm;
  for (int k = 0; k < F_; ++k) {
    float w = wr[k];
#pragma unroll
    for (int c = 0; c < C_; ++c) acc[c] += w * fl[c * F_ + k];
  }
  float wg = wgv[a];
  float ec[C_];
#pragma unroll
  for (int c = 0; c < C_; ++c) ec[c] = wg * tanhf(acc[c]);

#pragma unroll
  for (int s = 32; s >= 1; s >>= 1) {
#pragma unroll
    for (int c = 0; c < C_; ++c) ec[c] += __shfl_xor(ec[c], s);
  }
  if (tid == 0) {
#pragma unroll
    for (int c = 0; c < C_; ++c) e_part[(b * 5 + p) * C_ + c] = ec[c];
  }
}

// ---------------- Kernel 4: softmax + combine + tik-reg + solve + ws -----------
__global__ __launch_bounds__(64) void k_solve(
    const float2* __restrict__ psp, const float2* __restrict__ pnp,
    const float* __restrict__ msum, const float* __restrict__ nsum,
    const float* __restrict__ e_part, float2* __restrict__ wsv) {
  int bf = blockIdx.x;
  int b = bf / F_;
  int l = threadIdx.x;
  int r = l >> 3, q = l & 7;

  // softmax over channels (each 8-lane subgroup spans q=0..7)
  float e_c = 0.f;
#pragma unroll
  for (int p = 0; p < 5; ++p) e_c += e_part[(b * 5 + p) * C_ + q];
  e_c *= 2.0f;  // SCALING
  float mx = e_c;
#pragma unroll
  for (int s = 4; s >= 1; s >>= 1) mx = fmaxf(mx, __shfl_xor(mx, s));
  float ex = expf(e_c - mx);
  float sm = ex;
#pragma unroll
  for (int s = 4; s >= 1; s >>= 1) sm += __shfl_xor(sm, s);
  float uq = ex / sm;

  // combine halves + per-row mask normalization
  float2 M0 = pnp[(size_t)bf * 128 + l];
  float2 M1 = pnp[(size_t)bf * 128 + 64 + l];
  float2 R0 = psp[(size_t)bf * 128 + l];
  float2 R1 = psp[(size_t)bf * 128 + 64 + l];
  float nsr = nsum[bf * 16 + r] + nsum[bf * 16 + 8 + r];
  float msr = msum[bf * 16 + r] + msum[bf * 16 + 8 + r];
  float invn = 1.f / (nsr + 1e-6f);
  float invm = 1.f / (msr + 1e-6f);
  float2 M = make_float2((M0.x + M1.x) * invn, (M0.y + M1.y) * invn);
  float2 R = make_float2((R0.x + R1.x) * invm, (R0.y + R1.y) * invm);

  // trace(psd_n).real
  float td = (r == q) ? M.x : 0.f;
#pragma unroll
  for (int s = 32; s >= 1; s >>= 1) td += __shfl_xor(td, s);
  if (r == q) M.x += 1e-7f * (td * 0.125f) + 1e-8f;

  // Gauss-Jordan: M X = R  ->  R becomes X
#pragma unroll
  for (int k = 0; k < 8; ++k) {
    float pr = __shfl(M.x, k * 9), pi = __shfl(M.y, k * 9);
    float den = pr * pr + pi * pi;
    float ir = pr / den, ii = -pi / den;          // 1/pivot
    float mkr = __shfl(M.x, k * 8 + q), mki = __shfl(M.y, k * 8 + q);
    float rkr = __shfl(R.x, k * 8 + q), rki = __shfl(R.y, k * 8 + q);
    float gr = __shfl(M.x, r * 8 + k), gi = __shfl(M.y, r * 8 + k);
    if (r == k) {
      float nmr = M.x * ir - M.y * ii, nmi = M.x * ii + M.y * ir;
      float nrr = R.x * ir - R.y * ii, nri = R.x * ii + R.y * ir;
      M = make_float2(nmr, nmi); R = make_float2(nrr, nri);
    } else {
      float fr = gr * ir - gi * ii, fi = gr * ii + gi * ir;   // M[r,k]/pivot
      M.x -= fr * mkr - fi * mki; M.y -= fr * mki + fi * mkr;
      R.x -= fr * rkr - fi * rki; R.y -= fr * rki + fi * rkr;
    }
  }

  // trace(X), normalize, apply u
  float trr = (r == q) ? R.x : 0.f, tri = (r == q) ? R.y : 0.f;
#pragma unroll
  for (int s = 32; s >= 1; s >>= 1) { trr += __shfl_xor(trr, s); tri += __shfl_xor(tri, s); }
  trr += 1e-6f;  // + EPS (real)
  float den = trr * trr + tri * tri;
  float ir = trr / den, ii = -tri / den;
  float wr_ = R.x * ir - R.y * ii;   // ws_mat[r][q]
  float wi_ = R.x * ii + R.y * ir;
  float vr = wr_ * uq, vi = wi_ * uq;
#pragma unroll
  for (int s = 4; s >= 1; s >>= 1) { vr += __shfl_xor(vr, s); vi += __shfl_xor(vi, s); }
  if (q == 0) wsv[(size_t)bf * C_ + r] = make_float2(vr, vi);
}

// ---------------- Kernel 5: enhanced[b,t,f] = sum_c conj(ws) * x ----------------
__global__ __launch_bounds__(256) void k_bf(
    const float* __restrict__ dre, const float* __restrict__ dim_,
    const float2* __restrict__ wsv, float2* __restrict__ out) {
  __shared__ float2 wl[C_][F_];
  int blk = blockIdx.x;
  int b = blk / 125;
  int t0 = (blk - b * 125) * 8;
  int tid = threadIdx.x;
  // wsv layout [b][f][c] -> wl[c][f]
  for (int i = tid; i < C_ * F_; i += 256) {
    int f = i >> 3, c = i & 7;
    wl[c][f] = wsv[(size_t)b * (F_ * C_) + i];
  }
  __syncthreads();

  for (int dt = 0; dt < 8; ++dt) {
    int t = t0 + dt;
    const float* pr = dre + (size_t)(b * T_ + t) * (C_ * F_);
    const float* pi_ = dim_ + (size_t)(b * T_ + t) * (C_ * F_);
    for (int f = tid; f < F_; f += 256) {
      float ar = 0.f, ai = 0.f;
#pragma unroll
      for (int c = 0; c < C_; ++c) {
        float xr = pr[c * F_ + f], xi = pi_[c * F_ + f];
        float2 w = wl[c][f];
        ar += w.x * xr + w.y * xi;   // conj(w)*x
        ai += w.x * xi - w.y * xr;
      }
      out[(size_t)(b * T_ + t) * F_ + f] = make_float2(ar, ai);
    }
  }
}

extern "C" void kernel_launch(void* const* d_in, const int* in_sizes, int n_in,
                              void* d_out, int out_size, void* d_ws, size_t ws_size,
                              hipStream_t stream) {
  const float* dre = (const float*)d_in[0];
  const float* dim_ = (const float*)d_in[1];
  const float* ms = (const float*)d_in[2];
  const float* mn = (const float*)d_in[3];
  const float* wmlp = (const float*)d_in[4];
  const float* bmlp = (const float*)d_in[5];
  const float* wgv = (const float*)d_in[6];
  // d_in[7] = b_gvec: constant shift, cancels in softmax — unused.

  char* ws = (char*)d_ws;
  float2* xt   = (float2*)(ws);                 // 131,584,000 B
  float2* psp  = (float2*)(ws + 131584000);     // 2056*2*64*8 = 2,105,344 B
  float2* pnp  = (float2*)(ws + 133689344);     // 2,105,344 B
  float*  msum = (float*) (ws + 135794688);     // 131,584 B
  float*  nsum = (float*) (ws + 135926272);     // 131,584 B
  float*  feat = (float*) (ws + 136057856);     // 65,792 B
  float*  e_prt= (float*) (ws + 136123648);     // 1,280 B
  float2* wsv  = (float2*)(ws + 136124928);     // 131,584 B
                                                // end: 136,256,512 B

  dim3 g1(9, 32, B_ * C_), b1(32, 8, 1);
  k_transpose<<<g1, b1, 0, stream>>>(dre, dim_, xt);
  k_psd<<<1028, 256, 0, stream>>>(xt, ms, mn, psp, pnp, msum, nsum);
  k_comb<<<B_ * F_, 64, 0, stream>>>(psp, msum, feat);
  dim3 ga(B_, 5, 1);
  k_attn<<<ga, 64, 0, stream>>>(feat, wmlp, bmlp, wgv, e_prt);
  k_solve<<<B_ * F_, 64, 0, stream>>>(psp, pnp, msum, nsum, e_prt, wsv);
  k_bf<<<B_ * 125, 256, 0, stream>>>(dre, dim_, wsv, (float2*)d_out);
}

// Round 9
// 213.214 us; speedup vs baseline: 1.5759x; 1.5759x over previous
//
#include <hip/hip_runtime.h>
#include <math.h>

#define B_ 8
#define T_ 1000
#define C_ 8
#define F_ 257
#define A_ 320

// ---------------- Kernel 1: (B,T,C,F) -> (B,F,C,T) interleaved float2 ----------
// 64f x 32t tile per (b,c). Loads: 256B coalesced rows; stores: 256B coalesced
// t-runs. LDS pad 65 -> column read is 2-lanes/bank (free, m136).
__global__ __launch_bounds__(256) void k_transpose(
    const float* __restrict__ dre, const float* __restrict__ dim_,
    float2* __restrict__ xt) {
  __shared__ float2 tile[32][65];  // [t][f]
  int bc = blockIdx.z;
  int b = bc >> 3, c = bc & 7;
  int t0 = blockIdx.y * 32, f0 = blockIdx.x * 64;
  int tx = threadIdx.x & 63;       // f within tile
  int ty = threadIdx.x >> 6;       // t row base (4 rows/pass, 8 passes)
#pragma unroll
  for (int p = 0; p < 8; ++p) {
    int t = t0 + ty + p * 4;
    int f = f0 + tx;
    if (t < T_ && f < F_) {
      size_t idx = ((size_t)(b * T_ + t) * C_ + c) * F_ + f;
      tile[ty + p * 4][tx] = make_float2(dre[idx], dim_[idx]);
    }
  }
  __syncthreads();
  int tx2 = threadIdx.x & 31;      // t within tile
  int ty2 = threadIdx.x >> 5;      // f row base (8 rows/pass, 8 passes)
#pragma unroll
  for (int p = 0; p < 8; ++p) {
    int f = f0 + ty2 + p * 8;
    int t = t0 + tx2;
    if (t < T_ && f < F_) {
      xt[((size_t)(b * F_ + f) * C_ + c) * T_ + t] = tile[tx2][ty2 + p * 8];
    }
  }
}

// ---------------- Kernel 2: PSDs (both masks, one pass) + attention features ----
// r3 structure (benched 89us): CH=125 double-buffered LDS, 1-ahead register
// staging of x and masks. Inner loop pre-scaled: ys=m_s*x_c, yn=m_n*x_c once
// per t, then 8 pure FMAs per e (was 12 mixed ops).
#define CH_ 125
__global__ __launch_bounds__(256) void k_psd(
    const float2* __restrict__ xt,
    const float* __restrict__ ms, const float* __restrict__ mn,
    float2* __restrict__ psd_s, float2* __restrict__ psd_n,
    float* __restrict__ feat) {
  __shared__ float2 xl[2][C_][CH_];   // 16000 B
  int bf = blockIdx.x;            // b*F + f
  int b = bf / F_;
  int f = bf - b * F_;
  int tid = threadIdx.x;
  int g = tid >> 5;       // channel c owned by this 32-lane group
  int lane = tid & 31;

  const float2* xg = xt + (size_t)bf * (C_ * T_) + (size_t)g * T_;
  const float* msg = ms + (size_t)bf * (C_ * T_) + g * T_;
  const float* mng = mn + (size_t)bf * (C_ * T_) + g * T_;

  float2 xnx[4];            // staged x for next chunk
  float msx[4], mnx[4];     // staged masks for next chunk
  float ms4[4], mn4[4];     // masks for current chunk (registers)

  // prologue: chunk 0 -> regs -> LDS
#pragma unroll
  for (int it = 0; it < 4; ++it) {
    int tt = lane + it * 32;
    bool ok = tt < CH_;
    xnx[it] = ok ? xg[tt] : make_float2(0.f, 0.f);
    ms4[it] = ok ? msg[tt] : 0.f;
    mn4[it] = ok ? mng[tt] : 0.f;
  }
#pragma unroll
  for (int it = 0; it < 4; ++it) {
    int tt = lane + it * 32;
    if (tt < CH_) xl[0][g][tt] = xnx[it];
  }
  __syncthreads();

  float2 as_[C_], an_[C_];
#pragma unroll
  for (int e = 0; e < C_; ++e) { as_[e] = make_float2(0.f, 0.f); an_[e] = make_float2(0.f, 0.f); }
  float ss = 0.f, sn = 0.f;

  for (int ch = 0; ch < 8; ++ch) {
    int cur = ch & 1;
    // (1) issue next chunk's loads into registers (latency hides under compute)
    if (ch < 7) {
      int nbase = (ch + 1) * CH_;
#pragma unroll
      for (int it = 0; it < 4; ++it) {
        int tt = lane + it * 32;
        bool ok = tt < CH_;
        xnx[it] = ok ? xg[nbase + tt] : make_float2(0.f, 0.f);
        msx[it] = ok ? msg[nbase + tt] : 0.f;
        mnx[it] = ok ? mng[nbase + tt] : 0.f;
      }
    }
    // (2) compute current chunk from LDS + mask registers
#pragma unroll
    for (int it = 0; it < 4; ++it) {
      int tt = lane + it * 32;
      if (tt < CH_) {
        float vms = ms4[it], vmn = mn4[it];
        ss += vms; sn += vmn;
        float2 xc = xl[cur][g][tt];
        float ysx = vms * xc.x, ysy = vms * xc.y;   // m_s * x_c
        float ynx = vmn * xc.x, yny = vmn * xc.y;   // m_n * x_c
#pragma unroll
        for (int e = 0; e < C_; ++e) {
          float2 xe = xl[cur][e][tt];
          as_[e].x += ysx * xe.x + ysy * xe.y;   // m_s*(x_c conj(x_e)).re
          as_[e].y += ysy * xe.x - ysx * xe.y;   // .im
          an_[e].x += ynx * xe.x + yny * xe.y;
          an_[e].y += yny * xe.x - ynx * xe.y;
        }
      }
    }
    // (3) write staged x to the other LDS buffer, roll mask regs
    if (ch < 7) {
#pragma unroll
      for (int it = 0; it < 4; ++it) {
        int tt = lane + it * 32;
        if (tt < CH_) xl[cur ^ 1][g][tt] = xnx[it];
      }
#pragma unroll
      for (int it = 0; it < 4; ++it) { ms4[it] = msx[it]; mn4[it] = mnx[it]; }
    }
    // (4) one barrier per chunk
    __syncthreads();
  }

  // reduce across 32 lanes of the group (xor masks < 32 stay in-group)
#pragma unroll
  for (int s = 16; s >= 1; s >>= 1) {
    ss += __shfl_xor(ss, s);
    sn += __shfl_xor(sn, s);
#pragma unroll
    for (int e = 0; e < C_; ++e) {
      as_[e].x += __shfl_xor(as_[e].x, s);
      as_[e].y += __shfl_xor(as_[e].y, s);
      an_[e].x += __shfl_xor(an_[e].x, s);
      an_[e].y += __shfl_xor(an_[e].y, s);
    }
  }

  if (lane == 0) {
    float inv_s = 1.f / (ss + 1e-6f);
    float inv_n = 1.f / (sn + 1e-6f);
    float2* ps = psd_s + (size_t)bf * (C_ * C_) + g * C_;
    float2* pn = psd_n + (size_t)bf * (C_ * C_) + g * C_;
    float sr = 0.f, si = 0.f;
#pragma unroll
    for (int e = 0; e < C_; ++e) {
      float2 vs = make_float2(as_[e].x * inv_s, as_[e].y * inv_s);
      float2 vn = make_float2(an_[e].x * inv_n, an_[e].y * inv_n);
      ps[e] = vs; pn[e] = vn;
      if (e != g) { sr += vs.x; si += vs.y; }
    }
    sr *= (1.f / 7.f); si *= (1.f / 7.f);
    feat[(b * C_ + g) * F_ + f] = sqrtf(sr * sr + si * si);
  }
}

// ---------------- Kernel 3: attention MLP partial logits ----------------------
// grid (B, 5), block 64. b_gvec dropped (softmax-invariant).
__global__ __launch_bounds__(64) void k_attn(
    const float* __restrict__ feat, const float* __restrict__ wmlp,
    const float* __restrict__ bmlp, const float* __restrict__ wgv,
    float* __restrict__ e_part) {
  __shared__ float fl[C_ * F_];   // 8224 B
  int b = blockIdx.x, p = blockIdx.y;
  int tid = threadIdx.x;
  for (int i = tid; i < C_ * F_; i += 64) fl[i] = feat[b * C_ * F_ + i];
  __syncthreads();

  int a = p * 64 + tid;           // A = 320 = 5*64 exactly
  const float* wr = wmlp + a * F_;
  float acc[C_];
  float bm = bmlp[a];
#pragma unroll
  for (int c = 0; c < C_; ++c) acc[c] = bm;
  for (int k = 0; k < F_; ++k) {
    float w = wr[k];
#pragma unroll
    for (int c = 0; c < C_; ++c) acc[c] += w * fl[c * F_ + k];
  }
  float wg = wgv[a];
  float ec[C_];
#pragma unroll
  for (int c = 0; c < C_; ++c) ec[c] = wg * tanhf(acc[c]);

#pragma unroll
  for (int s = 32; s >= 1; s >>= 1) {
#pragma unroll
    for (int c = 0; c < C_; ++c) ec[c] += __shfl_xor(ec[c], s);
  }
  if (tid == 0) {
#pragma unroll
    for (int c = 0; c < C_; ++c) e_part[(b * 5 + p) * C_ + c] = ec[c];
  }
}

// ---------------- Kernel 4: softmax + tik-reg + 8x8 complex solve + ws ---------
__global__ __launch_bounds__(64) void k_solve(
    const float2* __restrict__ psd_s, const float2* __restrict__ psd_n,
    const float* __restrict__ e_part, float2* __restrict__ wsv) {
  int bf = blockIdx.x;
  int b = bf / F_;
  int l = threadIdx.x;
  int r = l >> 3, q = l & 7;

  // softmax over channels (each 8-lane subgroup spans q=0..7)
  float e_c = 0.f;
#pragma unroll
  for (int p = 0; p < 5; ++p) e_c += e_part[(b * 5 + p) * C_ + q];
  e_c *= 2.0f;  // SCALING
  float mx = e_c;
#pragma unroll
  for (int s = 4; s >= 1; s >>= 1) mx = fmaxf(mx, __shfl_xor(mx, s));
  float ex = expf(e_c - mx);
  float sm = ex;
#pragma unroll
  for (int s = 4; s >= 1; s >>= 1) sm += __shfl_xor(sm, s);
  float uq = ex / sm;

  float2 M = psd_n[(size_t)bf * 64 + l];
  float2 R = psd_s[(size_t)bf * 64 + l];

  // trace(psd_n).real
  float td = (r == q) ? M.x : 0.f;
#pragma unroll
  for (int s = 32; s >= 1; s >>= 1) td += __shfl_xor(td, s);
  if (r == q) M.x += 1e-7f * (td * 0.125f) + 1e-8f;

  // Gauss-Jordan: M X = R  ->  R becomes X
#pragma unroll
  for (int k = 0; k < 8; ++k) {
    float pr = __shfl(M.x, k * 9), pi = __shfl(M.y, k * 9);
    float den = pr * pr + pi * pi;
    float ir = pr / den, ii = -pi / den;          // 1/pivot
    float mkr = __shfl(M.x, k * 8 + q), mki = __shfl(M.y, k * 8 + q);
    float rkr = __shfl(R.x, k * 8 + q), rki = __shfl(R.y, k * 8 + q);
    float gr = __shfl(M.x, r * 8 + k), gi = __shfl(M.y, r * 8 + k);
    if (r == k) {
      float nmr = M.x * ir - M.y * ii, nmi = M.x * ii + M.y * ir;
      float nrr = R.x * ir - R.y * ii, nri = R.x * ii + R.y * ir;
      M = make_float2(nmr, nmi); R = make_float2(nrr, nri);
    } else {
      float fr = gr * ir - gi * ii, fi = gr * ii + gi * ir;   // M[r,k]/pivot
      M.x -= fr * mkr - fi * mki; M.y -= fr * mki + fi * mkr;
      R.x -= fr * rkr - fi * rki; R.y -= fr * rki + fi * rkr;
    }
  }

  // trace(X), normalize, apply u
  float trr = (r == q) ? R.x : 0.f, tri = (r == q) ? R.y : 0.f;
#pragma unroll
  for (int s = 32; s >= 1; s >>= 1) { trr += __shfl_xor(trr, s); tri += __shfl_xor(tri, s); }
  trr += 1e-6f;  // + EPS (real)
  float den = trr * trr + tri * tri;
  float ir = trr / den, ii = -tri / den;
  float wr_ = R.x * ir - R.y * ii;   // ws_mat[r][q]
  float wi_ = R.x * ii + R.y * ir;
  float vr = wr_ * uq, vi = wi_ * uq;
#pragma unroll
  for (int s = 4; s >= 1; s >>= 1) { vr += __shfl_xor(vr, s); vi += __shfl_xor(vi, s); }
  if (q == 0) wsv[(size_t)bf * C_ + r] = make_float2(vr, vi);
}

// ---------------- Kernel 5: enhanced[b,t,f] = sum_c conj(ws) * x ----------------
__global__ __launch_bounds__(256) void k_bf(
    const float* __restrict__ dre, const float* __restrict__ dim_,
    const float2* __restrict__ wsv, float2* __restrict__ out) {
  __shared__ float2 wl[C_][F_];
  int blk = blockIdx.x;
  int b = blk / 125;
  int t0 = (blk - b * 125) * 8;
  int tid = threadIdx.x;
  // wsv layout [b][f][c] -> wl[c][f]
  for (int i = tid; i < C_ * F_; i += 256) {
    int f = i >> 3, c = i & 7;
    wl[c][f] = wsv[(size_t)b * (F_ * C_) + i];
  }
  __syncthreads();

  for (int dt = 0; dt < 8; ++dt) {
    int t = t0 + dt;
    const float* pr = dre + (size_t)(b * T_ + t) * (C_ * F_);
    const float* pi_ = dim_ + (size_t)(b * T_ + t) * (C_ * F_);
    for (int f = tid; f < F_; f += 256) {
      float ar = 0.f, ai = 0.f;
#pragma unroll
      for (int c = 0; c < C_; ++c) {
        float xr = pr[c * F_ + f], xi = pi_[c * F_ + f];
        float2 w = wl[c][f];
        ar += w.x * xr + w.y * xi;   // conj(w)*x
        ai += w.x * xi - w.y * xr;
      }
      out[(size_t)(b * T_ + t) * F_ + f] = make_float2(ar, ai);
    }
  }
}

extern "C" void kernel_launch(void* const* d_in, const int* in_sizes, int n_in,
                              void* d_out, int out_size, void* d_ws, size_t ws_size,
                              hipStream_t stream) {
  const float* dre = (const float*)d_in[0];
  const float* dim_ = (const float*)d_in[1];
  const float* ms = (const float*)d_in[2];
  const float* mn = (const float*)d_in[3];
  const float* wmlp = (const float*)d_in[4];
  const float* bmlp = (const float*)d_in[5];
  const float* wgv = (const float*)d_in[6];
  // d_in[7] = b_gvec: constant shift, cancels in softmax — unused.

  char* ws = (char*)d_ws;
  float2* xt    = (float2*)(ws);                    // B*F*C*T float2 = 131,584,000 B
  float2* psd_s = (float2*)(ws + 131584000);        // 1,052,672 B
  float2* psd_n = (float2*)(ws + 132636672);        // 1,052,672 B
  float*  feat  = (float*) (ws + 133689344);        // 65,792 B
  float*  e_prt = (float*) (ws + 133755136);        // 1,280 B
  float2* wsv   = (float2*)(ws + 133756416);        // 131,584 B

  dim3 g1(5, 32, B_ * C_);
  k_transpose<<<g1, 256, 0, stream>>>(dre, dim_, xt);
  k_psd<<<B_ * F_, 256, 0, stream>>>(xt, ms, mn, psd_s, psd_n, feat);
  dim3 ga(B_, 5, 1);
  k_attn<<<ga, 64, 0, stream>>>(feat, wmlp, bmlp, wgv, e_prt);
  k_solve<<<B_ * F_, 64, 0, stream>>>(psd_s, psd_n, e_prt, wsv);
  k_bf<<<B_ * 125, 256, 0, stream>>>(dre, dim_, wsv, (float2*)d_out);
}